// Round 13
// baseline (147.855 us; speedup 1.0000x reference)
//
#include <hip/hip_runtime.h>
#include <cstdint>
#include <cstddef>

// DenseGAT, N=4096, IN_DIM=256, H=4, D=64, NEG_SLOPE=0.2
// w[i,j,h] = eb * max(t5, tt);  tt = ui*uj = exp(.2(ei+ej)),
//   t5 = ui5*uj5 = exp(ei+ej) = tt^5 (exact inputs), eb = exp(bias) or 0.
// max trick: tt>1 => t5>tt, tt<1 => t5<tt, so select == max. Row sums via
// an extra MFMA against a ones-B fragment (no serial VALU add chain).
//
// Attn history: R7 (64-row tile, (256,2), reg-dbuf ILP) = 41us, best.
//   R8-R12 (inline-exp, producer waves, preload order-flip) all neutral or
//   worse; R12's VGPR=124 proves the compiler re-sinks preloads -> the bias
//   DMA cannot be made truly async at HIP level (in-order vmcnt). attn=41
//   is this decomposition's floor. REVERTED to byte-exact R7 here.
// R13: gemm_wh was grid-capped (512 blocks = 2/CU, latency-bound, ~12us).
//   16-row tiles -> grid (4,256) = 1024 blocks = 4/CU, work/block halved.

typedef _Float16 f16x2 __attribute__((ext_vector_type(2)));
typedef _Float16 f16x4 __attribute__((ext_vector_type(4)));
typedef _Float16 f16x8 __attribute__((ext_vector_type(8)));
typedef float f32x4 __attribute__((ext_vector_type(4)));

#define NN 4096

// ---- Kernel 1: Wh = h @ W (fp32) + Vt (fp16 transpose) + ui/uj exps ------
// grid (4 heads, 256 row-tiles of 16), block 256.
__global__ __launch_bounds__(256) void gemm_wh(
    const float* __restrict__ A, const float* __restrict__ Bw,
    const float* __restrict__ av, float* __restrict__ C,
    _Float16* __restrict__ Vt,
    _Float16* __restrict__ uit, _Float16* __restrict__ ui5t,
    _Float16* __restrict__ ujt, _Float16* __restrict__ uj5t) {
  __shared__ float sA[32][20];      // [k][row], 16 rows + pad
  __shared__ float sB[32][68];      // [k][col]
  __shared__ _Float16 sT[64][28];   // transpose staging, 16 j + pad
  const int h  = blockIdx.x;
  const int by = blockIdx.y;
  const int t  = threadIdx.x;
  const int row0 = by * 16, col0 = h * 64;
  const int tc = t & 15, tr = t >> 4;      // cols tc*4..+3, row tr (0..15)
  float acc[4];
  #pragma unroll
  for (int p = 0; p < 4; p++) acc[p] = 0.f;

  for (int k0 = 0; k0 < 256; k0 += 32) {
    __syncthreads();
    if (t < 128) {                                 // A: 16x32
      const int r = t >> 3, k4 = (t & 7) * 4;
      float4 v = *(const float4*)&A[(size_t)(row0 + r) * 256 + k0 + k4];
      sA[k4 + 0][r] = v.x; sA[k4 + 1][r] = v.y;
      sA[k4 + 2][r] = v.z; sA[k4 + 3][r] = v.w;
    }
    #pragma unroll
    for (int q = 0; q < 2; q++) {                   // B: 32x64
      const int u = t + q * 256;
      const int kr = u >> 4, c4 = (u & 15) * 4;
      *(float4*)&sB[kr][c4] =
          *(const float4*)&Bw[(size_t)(k0 + kr) * 256 + col0 + c4];
    }
    __syncthreads();
    #pragma unroll
    for (int kk = 0; kk < 32; kk++) {
      const float a1 = sA[kk][tr];
      float4 bv = *(const float4*)&sB[kk][tc * 4];
      acc[0] = fmaf(a1, bv.x, acc[0]);
      acc[1] = fmaf(a1, bv.y, acc[1]);
      acc[2] = fmaf(a1, bv.z, acc[2]);
      acc[3] = fmaf(a1, bv.w, acc[3]);
    }
  }
  // C store (fp32 Wh)
  {
    float4 v = make_float4(acc[0], acc[1], acc[2], acc[3]);
    *(float4*)&C[(size_t)(row0 + tr) * 256 + col0 + tc * 4] = v;
  }
  // ei/ej: dot with a_i, a_j over the 64 cols of this head
  {
    float pi = 0.f, pj = 0.f;
    #pragma unroll
    for (int p = 0; p < 4; p++) {
      const int d = tc * 4 + p;
      pi = fmaf(acc[p], av[h * 128 + d], pi);
      pj = fmaf(acc[p], av[h * 128 + 64 + d], pj);
    }
    #pragma unroll
    for (int m = 1; m <= 8; m <<= 1) {
      pi += __shfl_xor(pi, m, 64);
      pj += __shfl_xor(pj, m, 64);
    }
    if (tc == 0) {
      const int row = row0 + tr;
      uit [(size_t)h * NN + row] = (_Float16)__expf(0.2f * pi);
      ui5t[(size_t)h * NN + row] = (_Float16)__expf(pi);       // = ui^5
      ujt [(size_t)h * NN + row] = (_Float16)__expf(0.2f * pj);
      uj5t[(size_t)h * NN + row] = (_Float16)__expf(pj);       // = uj^5
    }
  }
  // Vt transpose: Vt[col0+d][row0+j] fp16
  #pragma unroll
  for (int p = 0; p < 4; p++)
    sT[tc * 4 + p][tr] = (_Float16)acc[p];
  __syncthreads();
  {
    const int dd = t >> 2, j4 = (t & 3) * 4;
    f16x4 w;
    #pragma unroll
    for (int k = 0; k < 4; k++) w[k] = sT[dd][j4 + k];
    *(f16x4*)&Vt[(size_t)(col0 + dd) * NN + row0 + j4] = w;
  }
}

// ---- Kernel 2: fused attention (byte-exact R7: best measured, 41us) ------
// grid (64 i-tiles of 64, CH j-chunks), block 256 = 4 waves (wave = head).
// 2 blocks/CU, 256 regs/wave; explicit reg double-buffer of the s-loop.
__global__ __launch_bounds__(256, 2) void gat_attn(
    const float* __restrict__ bias, const _Float16* __restrict__ Vt,
    const _Float16* __restrict__ uit, const _Float16* __restrict__ ui5t,
    const _Float16* __restrict__ ujt, const _Float16* __restrict__ uj5t,
    float* __restrict__ P, float* __restrict__ L, int jpc) {
  __shared__ float rawb[64][128];        // raw bias tile, 32 KB, single buf
  __shared__ _Float16 seb[2][64][136];   // exp(bias) f16 tile, pad 8
  const int itile = blockIdx.x;
  const int chunk = blockIdx.y;
  const int tid = threadIdx.x;
  const int lane = tid & 63;
  const int h = __builtin_amdgcn_readfirstlane(tid >> 6);
  const int m = lane & 15;
  const int quad = lane >> 4;
  const int i0 = itile * 64;
  const int j0 = chunk * jpc;
  const int nc = jpc >> 7;

  f32x4 acc[4][5];                       // [it][dt0..3, ones-col]
  #pragma unroll
  for (int it = 0; it < 4; it++)
    #pragma unroll
    for (int dt = 0; dt < 5; dt++)
      #pragma unroll
      for (int r = 0; r < 4; r++) acc[it][dt][r] = 0.f;

  f16x8 ui8[4], u58[4];
  #pragma unroll
  for (int it = 0; it < 4; it++) {
    const _Float16 u1 = uit [(size_t)h * NN + i0 + it * 16 + m];
    const _Float16 u5 = ui5t[(size_t)h * NN + i0 + it * 16 + m];
    ui8[it] = (f16x8){u1, u1, u1, u1, u1, u1, u1, u1};
    u58[it] = (f16x8){u5, u5, u5, u5, u5, u5, u5, u5};
  }
  const f16x8 kOne = {(_Float16)1.f, (_Float16)1.f, (_Float16)1.f, (_Float16)1.f,
                      (_Float16)1.f, (_Float16)1.f, (_Float16)1.f, (_Float16)1.f};

  // --- async staging: per wave, 8x global_load_lds width=16 (2 rows each).
  // LDS dest is wave-uniform base + lane*16 (linear); global src is per-lane.
  const int lr = h * 16 + (lane >> 5);         // this lane's row (pair base)
  const int lc = lane & 31;                    // this lane's 16B chunk
  const float* gb = bias + (size_t)(i0 + lr) * NN + j0 + lc * 4;

  auto issue_load = [&](int jc) {
    const float* g = gb + jc * 128;
    #pragma unroll
    for (int q = 0; q < 8; q++) {
      __builtin_amdgcn_global_load_lds(
          (const __attribute__((address_space(1))) uint32_t*)(g + (size_t)(q * 2) * NN),
          (__attribute__((address_space(3))) uint32_t*)&rawb[h * 16 + q * 2][0],
          16, 0, 0);
    }
  };
  // --- convert: wave h converts its 16 rows; lane handles cols 2l, 2l+1.
  auto convert = [&](int buf) {
    #pragma unroll
    for (int rr = 0; rr < 16; rr++) {
      const int r = h * 16 + rr;
      const float2 v = *(const float2*)&rawb[r][lane * 2];
      f16x2 e;
      e[0] = (_Float16)((v.x == 0.f) ? 0.f : __expf(v.x));
      e[1] = (_Float16)((v.y == 0.f) ? 0.f : __expf(v.y));
      *(f16x2*)&seb[buf][r][lane * 2] = e;
    }
  };

  issue_load(0);
  __syncthreads();          // drains vmcnt -> rawb ready
  convert(0);

  const _Float16* vb  = Vt + (size_t)(h * 64 + m) * NN + j0 + quad * 8;
  const _Float16* ujb = ujt  + (size_t)h * NN + j0 + quad * 8;
  const _Float16* u5b = uj5t + (size_t)h * NN + j0 + quad * 8;

  for (int jc = 0; jc < nc; jc++) {
    const int buf = jc & 1;
    __syncthreads();        // seb[buf] visible; rawb free for next DMA
    if (jc + 1 < nc) issue_load(jc + 1);   // async DMA, hides under MFMAs

    const int jb = jc * 128;
    // --- preload s=0 operands into "current" regs
    f16x8 bc[4], ec[4], ujc, u5c;
    #pragma unroll
    for (int dt = 0; dt < 4; dt++)
      bc[dt] = *(const f16x8*)(vb + (size_t)(dt * 16) * NN + jb);
    ujc = *(const f16x8*)(ujb + jb);
    u5c = *(const f16x8*)(u5b + jb);
    #pragma unroll
    for (int it = 0; it < 4; it++)
      ec[it] = *(const f16x8*)&seb[buf][it * 16 + m][quad * 8];

    #pragma unroll
    for (int s = 0; s < 4; s++) {
      // --- prefetch s+1 while computing s (register double-buffer)
      f16x8 bn[4], en[4], ujn, u5n;
      if (s < 3) {
        const int off = jb + (s + 1) * 32;
        #pragma unroll
        for (int dt = 0; dt < 4; dt++)
          bn[dt] = *(const f16x8*)(vb + (size_t)(dt * 16) * NN + off);
        ujn = *(const f16x8*)(ujb + off);
        u5n = *(const f16x8*)(u5b + off);
        #pragma unroll
        for (int it = 0; it < 4; it++)
          en[it] = *(const f16x8*)&seb[buf][it * 16 + m][(s + 1) * 32 + quad * 8];
      }
      // w = eb * max(ui5*uj5, ui*uj)  — packed f16, whole-vector ops
      f16x8 a[4];
      #pragma unroll
      for (int it = 0; it < 4; it++)
        a[it] = ec[it] * __builtin_elementwise_max(u58[it] * u5c, ui8[it] * ujc);
      __builtin_amdgcn_s_setprio(1);
      #pragma unroll
      for (int it = 0; it < 4; it++) {
        #pragma unroll
        for (int dt = 0; dt < 4; dt++)
          acc[it][dt] = __builtin_amdgcn_mfma_f32_16x16x32_f16(a[it], bc[dt], acc[it][dt], 0, 0, 0);
        acc[it][4] = __builtin_amdgcn_mfma_f32_16x16x32_f16(a[it], kOne, acc[it][4], 0, 0, 0);
      }
      __builtin_amdgcn_s_setprio(0);
      if (s < 3) {
        #pragma unroll
        for (int dt = 0; dt < 4; dt++) bc[dt] = bn[dt];
        #pragma unroll
        for (int it = 0; it < 4; it++) ec[it] = en[it];
        ujc = ujn; u5c = u5n;
      }
    }

    __syncthreads();        // drains global_load_lds; all waves done w/ seb
    if (jc + 1 < nc) convert(buf ^ 1);
  }

  // epilogue: partials
  const size_t lb = (size_t)(chunk * 4 + h) * NN + i0;
  if (m == 0) {
    #pragma unroll
    for (int it = 0; it < 4; it++)
      #pragma unroll
      for (int r = 0; r < 4; r++)
        L[lb + it * 16 + quad * 4 + r] = acc[it][4][r];
  }
  const size_t pbase = ((size_t)(chunk * 4 + h) * NN + i0) * 64;
  #pragma unroll
  for (int it = 0; it < 4; it++)
    #pragma unroll
    for (int dt = 0; dt < 4; dt++)
      #pragma unroll
      for (int r = 0; r < 4; r++)
        P[pbase + (size_t)(it * 16 + quad * 4 + r) * 64 + dt * 16 + m] = acc[it][dt][r];
}

// ---- Kernel 3: reduce partials, normalize, ELU (float2-vectorized) -------
// grid (256 i-tiles of 16, 4 heads), block 256.
template <int CHT>
__global__ __launch_bounds__(256) void reduce_out(
    const float* __restrict__ P, const float* __restrict__ L,
    const float* __restrict__ Wh, float* __restrict__ out) {
  const int i0 = blockIdx.x * 16;
  const int h = blockIdx.y;
  const int t = threadIdx.x;
  const int d2 = (t & 31) * 2;
  const int isub = t >> 5;              // 8 groups of 2 rows
  #pragma unroll
  for (int ii = 0; ii < 2; ii++) {
    const int i = i0 + isub * 2 + ii;
    float lsum = 0.f;
    float sx = 0.f, sy = 0.f;
    #pragma unroll
    for (int c = 0; c < CHT; c++) {
      lsum += L[(size_t)(c * 4 + h) * NN + i];
      const float2 p = *(const float2*)&P[((size_t)(c * 4 + h) * NN + i) * 64 + d2];
      sx += p.x; sy += p.y;
    }
    const float2 wh = *(const float2*)&Wh[(size_t)i * 256 + h * 64 + d2];
    const bool fb = (lsum == 0.f);
    float ox = fb ? wh.x : sx / lsum;
    float oy = fb ? wh.y : sy / lsum;
    ox = (ox > 0.f) ? ox : (__expf(ox) - 1.f);
    oy = (oy > 0.f) ? oy : (__expf(oy) - 1.f);
    float2 o = make_float2(ox, oy);
    *(float2*)&out[(size_t)i * 256 + h * 64 + d2] = o;
  }
}

extern "C" void kernel_launch(void* const* d_in, const int* in_sizes, int n_in,
                              void* d_out, int out_size, void* d_ws, size_t ws_size,
                              hipStream_t stream) {
  const float* h_in = (const float*)d_in[0];   // (4096, 256)
  const float* adj  = (const float*)d_in[1];   // (4096, 4096)
  const float* W    = (const float*)d_in[2];   // (256, 256)
  const float* a    = (const float*)d_in[3];   // (4, 128)
  float* out = (float*)d_out;
  float* ws = (float*)d_ws;

  int CH = 8;
  while (CH > 1) {
    size_t floats = 1048576 /*Wh*/ + 524288 /*Vt f16*/ + 32768 /*u arrays*/ +
                    (size_t)CH * (16384 + 1048576);
    if (floats * 4 <= ws_size) break;
    CH >>= 1;
  }
  const int jpc = NN / CH;

  float* Wh = ws;
  _Float16* Vt   = (_Float16*)(ws + 1048576);
  _Float16* uit  = (_Float16*)(ws + 1048576 + 524288);
  _Float16* ui5t = uit + 16384;
  _Float16* ujt  = ui5t + 16384;
  _Float16* uj5t = ujt + 16384;
  float* Lb = ws + 1048576 + 524288 + 32768;
  float* Pb = Lb + (size_t)CH * 16384;

  hipLaunchKernelGGL(gemm_wh, dim3(4, 256), dim3(256), 0, stream,
                     h_in, W, a, Wh, Vt, uit, ui5t, ujt, uj5t);
  hipLaunchKernelGGL(gat_attn, dim3(64, CH), dim3(256), 0, stream,
                     adj, Vt, uit, ui5t, ujt, uj5t, Pb, Lb, jpc);
  switch (CH) {
    case 8: hipLaunchKernelGGL((reduce_out<8>), dim3(256, 4), dim3(256), 0, stream, Pb, Lb, Wh, out); break;
    case 4: hipLaunchKernelGGL((reduce_out<4>), dim3(256, 4), dim3(256), 0, stream, Pb, Lb, Wh, out); break;
    case 2: hipLaunchKernelGGL((reduce_out<2>), dim3(256, 4), dim3(256), 0, stream, Pb, Lb, Wh, out); break;
    default: hipLaunchKernelGGL((reduce_out<1>), dim3(256, 4), dim3(256), 0, stream, Pb, Lb, Wh, out); break;
  }
}

// Round 14
// 143.773 us; speedup vs baseline: 1.0284x; 1.0284x over previous
//
#include <hip/hip_runtime.h>
#include <cstdint>
#include <cstddef>

// DenseGAT, N=4096, IN_DIM=256, H=4, D=64, NEG_SLOPE=0.2
// w[i,j,h] = eb * max(t5, tt);  tt = ui*uj = exp(.2(ei+ej)),
//   t5 = ui5*uj5 = exp(ei+ej) = tt^5 (exact inputs), eb = exp(bias) or 0.
// max trick: tt>1 => t5>tt, tt<1 => t5<tt, so select == max. Row sums via
// an extra MFMA against a ones-B fragment (no serial VALU add chain).
//
// FINAL CONFIG (= R7, measured 144.5us total; attn 41.1us):
//   attn: 64-row i-tile, (256,2) fat waves (124 VGPR + 80 acc), reg-dbuf
//     s-loop, DMA-staged bias, CH=8. Proven floor: thin-wave/high-occupancy
//     (R0-R4), producer-split (R10/R11), order-flip (R12), no-LDS (R5) all
//     measured worse; in-order vmcnt makes one bias drain per chunk
//     irreducible at HIP level with this register budget.
//   gemm: 32-row tiles (R13's 16-row variant was -3us: half-idle A-staging).
//   Budget: harness fills 82us (HBM roofline) + attn 41 + gemm ~10 + reduce
//     ~7 + gaps = ~145us.

typedef _Float16 f16x2 __attribute__((ext_vector_type(2)));
typedef _Float16 f16x4 __attribute__((ext_vector_type(4)));
typedef _Float16 f16x8 __attribute__((ext_vector_type(8)));
typedef float f32x4 __attribute__((ext_vector_type(4)));

#define NN 4096

// ---- Kernel 1: Wh = h @ W (fp32) + Vt (fp16 transpose) + ui/uj exps ------
// grid (4 heads, 128 row-tiles of 32), block 256.
__global__ __launch_bounds__(256) void gemm_wh(
    const float* __restrict__ A, const float* __restrict__ Bw,
    const float* __restrict__ av, float* __restrict__ C,
    _Float16* __restrict__ Vt,
    _Float16* __restrict__ uit, _Float16* __restrict__ ui5t,
    _Float16* __restrict__ ujt, _Float16* __restrict__ uj5t) {
  __shared__ float sA[32][36];      // [k][row]
  __shared__ float sB[32][68];      // [k][col]
  __shared__ _Float16 sT[64][40];   // transpose staging
  const int h  = blockIdx.x;
  const int by = blockIdx.y;
  const int t  = threadIdx.x;
  const int row0 = by * 32, col0 = h * 64;
  const int tc = t & 15, tr = t >> 4;      // cols tc*4..+3, rows tr*2..+1
  float acc[2][4];
  #pragma unroll
  for (int q = 0; q < 2; q++)
    #pragma unroll
    for (int p = 0; p < 4; p++) acc[q][p] = 0.f;

  for (int k0 = 0; k0 < 256; k0 += 32) {
    __syncthreads();
    {
      const int r = t >> 3, k4 = (t & 7) * 4;      // A: 32x32
      float4 v = *(const float4*)&A[(size_t)(row0 + r) * 256 + k0 + k4];
      sA[k4 + 0][r] = v.x; sA[k4 + 1][r] = v.y;
      sA[k4 + 2][r] = v.z; sA[k4 + 3][r] = v.w;
    }
    #pragma unroll
    for (int q = 0; q < 2; q++) {                   // B: 32x64
      const int u = t + q * 256;
      const int kr = u >> 4, c4 = (u & 15) * 4;
      *(float4*)&sB[kr][c4] =
          *(const float4*)&Bw[(size_t)(k0 + kr) * 256 + col0 + c4];
    }
    __syncthreads();
    #pragma unroll
    for (int kk = 0; kk < 32; kk++) {
      float2 a2 = *(const float2*)&sA[kk][tr * 2];
      float4 bv = *(const float4*)&sB[kk][tc * 4];
      const float bp[4] = {bv.x, bv.y, bv.z, bv.w};
      #pragma unroll
      for (int p = 0; p < 4; p++) {
        acc[0][p] = fmaf(a2.x, bp[p], acc[0][p]);
        acc[1][p] = fmaf(a2.y, bp[p], acc[1][p]);
      }
    }
  }
  // C store (fp32 Wh)
  #pragma unroll
  for (int q = 0; q < 2; q++) {
    float4 v = make_float4(acc[q][0], acc[q][1], acc[q][2], acc[q][3]);
    *(float4*)&C[(size_t)(row0 + tr * 2 + q) * 256 + col0 + tc * 4] = v;
  }
  // ei/ej: dot with a_i, a_j over the 64 cols of this head
  {
    float pi[2] = {0.f, 0.f}, pj[2] = {0.f, 0.f};
    #pragma unroll
    for (int q = 0; q < 2; q++)
      #pragma unroll
      for (int p = 0; p < 4; p++) {
        const int d = tc * 4 + p;
        pi[q] = fmaf(acc[q][p], av[h * 128 + d], pi[q]);
        pj[q] = fmaf(acc[q][p], av[h * 128 + 64 + d], pj[q]);
      }
    #pragma unroll
    for (int m = 1; m <= 8; m <<= 1) {
      #pragma unroll
      for (int q = 0; q < 2; q++) {
        pi[q] += __shfl_xor(pi[q], m, 64);
        pj[q] += __shfl_xor(pj[q], m, 64);
      }
    }
    if (tc == 0) {
      #pragma unroll
      for (int q = 0; q < 2; q++) {
        const int row = row0 + tr * 2 + q;
        uit [(size_t)h * NN + row] = (_Float16)__expf(0.2f * pi[q]);
        ui5t[(size_t)h * NN + row] = (_Float16)__expf(pi[q]);       // = ui^5
        ujt [(size_t)h * NN + row] = (_Float16)__expf(0.2f * pj[q]);
        uj5t[(size_t)h * NN + row] = (_Float16)__expf(pj[q]);       // = uj^5
      }
    }
  }
  // Vt transpose: Vt[col0+d][row0+j] fp16
  #pragma unroll
  for (int q = 0; q < 2; q++)
    #pragma unroll
    for (int p = 0; p < 4; p++)
      sT[tc * 4 + p][tr * 2 + q] = (_Float16)acc[q][p];
  __syncthreads();
  {
    const int dd = t >> 2, j8 = (t & 3) * 8;
    f16x8 w;
    #pragma unroll
    for (int k = 0; k < 8; k++) w[k] = sT[dd][j8 + k];
    *(f16x8*)&Vt[(size_t)(col0 + dd) * NN + row0 + j8] = w;
  }
}

// ---- Kernel 2: fused attention (byte-exact R7: best measured, 41us) ------
// grid (64 i-tiles of 64, CH j-chunks), block 256 = 4 waves (wave = head).
// 2 blocks/CU, 256 regs/wave; explicit reg double-buffer of the s-loop.
__global__ __launch_bounds__(256, 2) void gat_attn(
    const float* __restrict__ bias, const _Float16* __restrict__ Vt,
    const _Float16* __restrict__ uit, const _Float16* __restrict__ ui5t,
    const _Float16* __restrict__ ujt, const _Float16* __restrict__ uj5t,
    float* __restrict__ P, float* __restrict__ L, int jpc) {
  __shared__ float rawb[64][128];        // raw bias tile, 32 KB, single buf
  __shared__ _Float16 seb[2][64][136];   // exp(bias) f16 tile, pad 8
  const int itile = blockIdx.x;
  const int chunk = blockIdx.y;
  const int tid = threadIdx.x;
  const int lane = tid & 63;
  const int h = __builtin_amdgcn_readfirstlane(tid >> 6);
  const int m = lane & 15;
  const int quad = lane >> 4;
  const int i0 = itile * 64;
  const int j0 = chunk * jpc;
  const int nc = jpc >> 7;

  f32x4 acc[4][5];                       // [it][dt0..3, ones-col]
  #pragma unroll
  for (int it = 0; it < 4; it++)
    #pragma unroll
    for (int dt = 0; dt < 5; dt++)
      #pragma unroll
      for (int r = 0; r < 4; r++) acc[it][dt][r] = 0.f;

  f16x8 ui8[4], u58[4];
  #pragma unroll
  for (int it = 0; it < 4; it++) {
    const _Float16 u1 = uit [(size_t)h * NN + i0 + it * 16 + m];
    const _Float16 u5 = ui5t[(size_t)h * NN + i0 + it * 16 + m];
    ui8[it] = (f16x8){u1, u1, u1, u1, u1, u1, u1, u1};
    u58[it] = (f16x8){u5, u5, u5, u5, u5, u5, u5, u5};
  }
  const f16x8 kOne = {(_Float16)1.f, (_Float16)1.f, (_Float16)1.f, (_Float16)1.f,
                      (_Float16)1.f, (_Float16)1.f, (_Float16)1.f, (_Float16)1.f};

  // --- async staging: per wave, 8x global_load_lds width=16 (2 rows each).
  // LDS dest is wave-uniform base + lane*16 (linear); global src is per-lane.
  const int lr = h * 16 + (lane >> 5);         // this lane's row (pair base)
  const int lc = lane & 31;                    // this lane's 16B chunk
  const float* gb = bias + (size_t)(i0 + lr) * NN + j0 + lc * 4;

  auto issue_load = [&](int jc) {
    const float* g = gb + jc * 128;
    #pragma unroll
    for (int q = 0; q < 8; q++) {
      __builtin_amdgcn_global_load_lds(
          (const __attribute__((address_space(1))) uint32_t*)(g + (size_t)(q * 2) * NN),
          (__attribute__((address_space(3))) uint32_t*)&rawb[h * 16 + q * 2][0],
          16, 0, 0);
    }
  };
  // --- convert: wave h converts its 16 rows; lane handles cols 2l, 2l+1.
  auto convert = [&](int buf) {
    #pragma unroll
    for (int rr = 0; rr < 16; rr++) {
      const int r = h * 16 + rr;
      const float2 v = *(const float2*)&rawb[r][lane * 2];
      f16x2 e;
      e[0] = (_Float16)((v.x == 0.f) ? 0.f : __expf(v.x));
      e[1] = (_Float16)((v.y == 0.f) ? 0.f : __expf(v.y));
      *(f16x2*)&seb[buf][r][lane * 2] = e;
    }
  };

  issue_load(0);
  __syncthreads();          // drains vmcnt -> rawb ready
  convert(0);

  const _Float16* vb  = Vt + (size_t)(h * 64 + m) * NN + j0 + quad * 8;
  const _Float16* ujb = ujt  + (size_t)h * NN + j0 + quad * 8;
  const _Float16* u5b = uj5t + (size_t)h * NN + j0 + quad * 8;

  for (int jc = 0; jc < nc; jc++) {
    const int buf = jc & 1;
    __syncthreads();        // seb[buf] visible; rawb free for next DMA
    if (jc + 1 < nc) issue_load(jc + 1);   // async DMA, hides under MFMAs

    const int jb = jc * 128;
    // --- preload s=0 operands into "current" regs
    f16x8 bc[4], ec[4], ujc, u5c;
    #pragma unroll
    for (int dt = 0; dt < 4; dt++)
      bc[dt] = *(const f16x8*)(vb + (size_t)(dt * 16) * NN + jb);
    ujc = *(const f16x8*)(ujb + jb);
    u5c = *(const f16x8*)(u5b + jb);
    #pragma unroll
    for (int it = 0; it < 4; it++)
      ec[it] = *(const f16x8*)&seb[buf][it * 16 + m][quad * 8];

    #pragma unroll
    for (int s = 0; s < 4; s++) {
      // --- prefetch s+1 while computing s (register double-buffer)
      f16x8 bn[4], en[4], ujn, u5n;
      if (s < 3) {
        const int off = jb + (s + 1) * 32;
        #pragma unroll
        for (int dt = 0; dt < 4; dt++)
          bn[dt] = *(const f16x8*)(vb + (size_t)(dt * 16) * NN + off);
        ujn = *(const f16x8*)(ujb + off);
        u5n = *(const f16x8*)(u5b + off);
        #pragma unroll
        for (int it = 0; it < 4; it++)
          en[it] = *(const f16x8*)&seb[buf][it * 16 + m][(s + 1) * 32 + quad * 8];
      }
      // w = eb * max(ui5*uj5, ui*uj)  — packed f16, whole-vector ops
      f16x8 a[4];
      #pragma unroll
      for (int it = 0; it < 4; it++)
        a[it] = ec[it] * __builtin_elementwise_max(u58[it] * u5c, ui8[it] * ujc);
      __builtin_amdgcn_s_setprio(1);
      #pragma unroll
      for (int it = 0; it < 4; it++) {
        #pragma unroll
        for (int dt = 0; dt < 4; dt++)
          acc[it][dt] = __builtin_amdgcn_mfma_f32_16x16x32_f16(a[it], bc[dt], acc[it][dt], 0, 0, 0);
        acc[it][4] = __builtin_amdgcn_mfma_f32_16x16x32_f16(a[it], kOne, acc[it][4], 0, 0, 0);
      }
      __builtin_amdgcn_s_setprio(0);
      if (s < 3) {
        #pragma unroll
        for (int dt = 0; dt < 4; dt++) bc[dt] = bn[dt];
        #pragma unroll
        for (int it = 0; it < 4; it++) ec[it] = en[it];
        ujc = ujn; u5c = u5n;
      }
    }

    __syncthreads();        // drains global_load_lds; all waves done w/ seb
    if (jc + 1 < nc) convert(buf ^ 1);
  }

  // epilogue: partials
  const size_t lb = (size_t)(chunk * 4 + h) * NN + i0;
  if (m == 0) {
    #pragma unroll
    for (int it = 0; it < 4; it++)
      #pragma unroll
      for (int r = 0; r < 4; r++)
        L[lb + it * 16 + quad * 4 + r] = acc[it][4][r];
  }
  const size_t pbase = ((size_t)(chunk * 4 + h) * NN + i0) * 64;
  #pragma unroll
  for (int it = 0; it < 4; it++)
    #pragma unroll
    for (int dt = 0; dt < 4; dt++)
      #pragma unroll
      for (int r = 0; r < 4; r++)
        P[pbase + (size_t)(it * 16 + quad * 4 + r) * 64 + dt * 16 + m] = acc[it][dt][r];
}

// ---- Kernel 3: reduce partials, normalize, ELU (float2-vectorized) -------
// grid (256 i-tiles of 16, 4 heads), block 256.
template <int CHT>
__global__ __launch_bounds__(256) void reduce_out(
    const float* __restrict__ P, const float* __restrict__ L,
    const float* __restrict__ Wh, float* __restrict__ out) {
  const int i0 = blockIdx.x * 16;
  const int h = blockIdx.y;
  const int t = threadIdx.x;
  const int d2 = (t & 31) * 2;
  const int isub = t >> 5;              // 8 groups of 2 rows
  #pragma unroll
  for (int ii = 0; ii < 2; ii++) {
    const int i = i0 + isub * 2 + ii;
    float lsum = 0.f;
    float sx = 0.f, sy = 0.f;
    #pragma unroll
    for (int c = 0; c < CHT; c++) {
      lsum += L[(size_t)(c * 4 + h) * NN + i];
      const float2 p = *(const float2*)&P[((size_t)(c * 4 + h) * NN + i) * 64 + d2];
      sx += p.x; sy += p.y;
    }
    const float2 wh = *(const float2*)&Wh[(size_t)i * 256 + h * 64 + d2];
    const bool fb = (lsum == 0.f);
    float ox = fb ? wh.x : sx / lsum;
    float oy = fb ? wh.y : sy / lsum;
    ox = (ox > 0.f) ? ox : (__expf(ox) - 1.f);
    oy = (oy > 0.f) ? oy : (__expf(oy) - 1.f);
    float2 o = make_float2(ox, oy);
    *(float2*)&out[(size_t)i * 256 + h * 64 + d2] = o;
  }
}

extern "C" void kernel_launch(void* const* d_in, const int* in_sizes, int n_in,
                              void* d_out, int out_size, void* d_ws, size_t ws_size,
                              hipStream_t stream) {
  const float* h_in = (const float*)d_in[0];   // (4096, 256)
  const float* adj  = (const float*)d_in[1];   // (4096, 4096)
  const float* W    = (const float*)d_in[2];   // (256, 256)
  const float* a    = (const float*)d_in[3];   // (4, 128)
  float* out = (float*)d_out;
  float* ws = (float*)d_ws;

  int CH = 8;
  while (CH > 1) {
    size_t floats = 1048576 /*Wh*/ + 524288 /*Vt f16*/ + 32768 /*u arrays*/ +
                    (size_t)CH * (16384 + 1048576);
    if (floats * 4 <= ws_size) break;
    CH >>= 1;
  }
  const int jpc = NN / CH;

  float* Wh = ws;
  _Float16* Vt   = (_Float16*)(ws + 1048576);
  _Float16* uit  = (_Float16*)(ws + 1048576 + 524288);
  _Float16* ui5t = uit + 16384;
  _Float16* ujt  = ui5t + 16384;
  _Float16* uj5t = ujt + 16384;
  float* Lb = ws + 1048576 + 524288 + 32768;
  float* Pb = Lb + (size_t)CH * 16384;

  hipLaunchKernelGGL(gemm_wh, dim3(4, 128), dim3(256), 0, stream,
                     h_in, W, a, Wh, Vt, uit, ui5t, ujt, uj5t);
  hipLaunchKernelGGL(gat_attn, dim3(64, CH), dim3(256), 0, stream,
                     adj, Vt, uit, ui5t, ujt, uj5t, Pb, Lb, jpc);
  switch (CH) {
    case 8: hipLaunchKernelGGL((reduce_out<8>), dim3(256, 4), dim3(256), 0, stream, Pb, Lb, Wh, out); break;
    case 4: hipLaunchKernelGGL((reduce_out<4>), dim3(256, 4), dim3(256), 0, stream, Pb, Lb, Wh, out); break;
    case 2: hipLaunchKernelGGL((reduce_out<2>), dim3(256, 4), dim3(256), 0, stream, Pb, Lb, Wh, out); break;
    default: hipLaunchKernelGGL((reduce_out<1>), dim3(256, 4), dim3(256), 0, stream, Pb, Lb, Wh, out); break;
  }
}